// Round 2
// baseline (294.302 us; speedup 1.0000x reference)
//
#include <hip/hip_runtime.h>
#include <hip/hip_bf16.h>
#include <cstdint>

#define D_MODEL 1024
#define NHEAD 16
#define DKH 64
#define BATCH 4
#define SEQ 2048
#define M_TOT (BATCH*SEQ)   // 8192

typedef __bf16 bf16;
typedef __bf16 bf16x8 __attribute__((ext_vector_type(8)));
typedef __bf16 bf16x4 __attribute__((ext_vector_type(4)));
typedef float  f32x4  __attribute__((ext_vector_type(4)));
typedef float  f32x16 __attribute__((ext_vector_type(16)));

// async global->LDS, 16B per lane. LDS dest must be wave-uniform base; HW adds lane*16.
__device__ __forceinline__ void async_ld16(const void* g, void* l) {
    __builtin_amdgcn_global_load_lds(
        (__attribute__((address_space(1))) void*)(uintptr_t)g,
        (__attribute__((address_space(3))) void*)(uintptr_t)l,
        16, 0, 0);
}

__device__ __forceinline__ unsigned pack2_bf16(float lo, float hi) {
    union { __bf16 h[2]; unsigned u; } w;
    w.h[0] = (bf16)lo; w.h[1] = (bf16)hi;
    return w.u;   // low 16 = lo (even key), high 16 = hi
}

// ---------------- merged convert: x fp32->bf16 (blocks 0..8191) and
// weight convert+transpose W[K][N] fp32 -> Wt[N][K] bf16 (blocks 8192..12287) ----------------
__global__ __launch_bounds__(256) void k_cvt(const float* __restrict__ x,
                                             bf16* __restrict__ xb,
                                             const float* __restrict__ wq,
                                             const float* __restrict__ wk,
                                             const float* __restrict__ wv,
                                             const float* __restrict__ wo,
                                             bf16* __restrict__ wt) {
    __shared__ float t[32][33];
    int bid = blockIdx.x;
    if (bid < 8192) {
        int i = (bid * 256 + threadIdx.x) * 4;
        float4 f = *(const float4*)(x + i);
        bf16x4 o;
        o[0] = (bf16)f.x; o[1] = (bf16)f.y; o[2] = (bf16)f.z; o[3] = (bf16)f.w;
        *(bf16x4*)(xb + i) = o;
    } else {
        int wb = bid - 8192;                  // 0..4095
        int z = wb >> 10;
        int rem = wb & 1023;
        const float* W = (z == 0) ? wq : (z == 1) ? wk : (z == 2) ? wv : wo;
        bf16* T = wt + (size_t)z * D_MODEL * D_MODEL;
        int tx = threadIdx.x & 31, ty = threadIdx.x >> 5;   // (32,8)
        int bx = (rem & 31) * 32, by = (rem >> 5) * 32;
#pragma unroll
        for (int i = 0; i < 4; i++)
            t[ty + i * 8][tx] = W[(size_t)(by + ty + i * 8) * D_MODEL + bx + tx];
        __syncthreads();
#pragma unroll
        for (int i = 0; i < 4; i++)
            T[(size_t)(bx + ty + i * 8) * D_MODEL + by + tx] = (bf16)t[tx][ty + i * 8];
    }
}

// ---------------- fused QKV GEMM, z-merged + XCD-swizzled + BK=64 ----------------
// Grid (64 m-tiles, 24 n-tiles over 3072 cols). id = bx + 64*by -> id%8 = bx%8:
// all n-tiles of one m-tile run on the SAME XCD -> A-tile HBM-fetched once.
// NOTE R6 lesson: NO min-waves launch bound — forcing 4 waves/SIMD on a
// ~120-VGPR kernel spilled acc to scratch (WRITE_SIZE 49MB->1.4GB, 5x slower).
__global__ __launch_bounds__(256) void k_gemm_qkv(const bf16* __restrict__ xb,
                                                  const bf16* __restrict__ wt,
                                                  const float* __restrict__ bq,
                                                  const float* __restrict__ bk,
                                                  const float* __restrict__ bv,
                                                  bf16* __restrict__ qkv,
                                                  bf16* __restrict__ vtg) {
    __shared__ bf16 As[2 * 128 * 32];   // 16 KB: two 32-wide k-panels
    __shared__ bf16 Bs[2 * 128 * 32];   // 16 KB

    int tid = threadIdx.x;
    int lane = tid & 63, wid = tid >> 6;
    int ln = lane & 15, qd = lane >> 4;
    int wm = wid >> 1, wn = wid & 1;
    int m0 = blockIdx.x * 128;                 // m-tile (x-fastest -> XCD pin)
    int n0 = blockIdx.y * 128;                 // global col in [0,3072)
    int z = n0 >> 10;
    const float* bias = (z == 0) ? bq : (z == 1) ? bk : bv;
    float scale = (z == 0) ? 0.125f * 1.44269504088896f : 1.0f;  // 1/sqrt(Dk)*log2e folded into Q
    bool swapped = (z < 2);

    f32x4 zero4 = {0.f, 0.f, 0.f, 0.f};
    f32x4 acc[4][4];
#pragma unroll
    for (int i = 0; i < 4; i++)
#pragma unroll
        for (int j = 0; j < 4; j++) acc[i][j] = zero4;

    for (int k0 = 0; k0 < D_MODEL; k0 += 64) {
#pragma unroll
        for (int t = 0; t < 4; t++) {
            int c = t * 256 + tid;             // 0..1023, 16B each
            int ch = c >> 9, w = c & 511;      // panel, slot
            int row = w >> 2, part = w & 3;
            async_ld16(xb + (size_t)(m0 + row) * D_MODEL + k0 + ch * 32 + part * 8,
                       As + ch * 4096 + (w & ~63) * 8);
            async_ld16(wt + (size_t)(n0 + row) * D_MODEL + k0 + ch * 32 + part * 8,
                       Bs + ch * 4096 + (w & ~63) * 8);
        }
        __syncthreads();
#pragma unroll
        for (int kc = 0; kc < 2; kc++) {
            bf16x8 af[4], bfr[4];
#pragma unroll
            for (int mi = 0; mi < 4; mi++)
                af[mi] = *(const bf16x8*)(As + kc * 4096 + (wm * 64 + mi * 16 + ln) * 32 + qd * 8);
#pragma unroll
            for (int ni = 0; ni < 4; ni++)
                bfr[ni] = *(const bf16x8*)(Bs + kc * 4096 + (wn * 64 + ni * 16 + ln) * 32 + qd * 8);
            if (swapped) {
#pragma unroll
                for (int mi = 0; mi < 4; mi++)
#pragma unroll
                    for (int ni = 0; ni < 4; ni++)
                        acc[mi][ni] = __builtin_amdgcn_mfma_f32_16x16x32_bf16(bfr[ni], af[mi],
                                                                              acc[mi][ni], 0, 0, 0);
            } else {
#pragma unroll
                for (int mi = 0; mi < 4; mi++)
#pragma unroll
                    for (int ni = 0; ni < 4; ni++)
                        acc[mi][ni] = __builtin_amdgcn_mfma_f32_16x16x32_bf16(af[mi], bfr[ni],
                                                                              acc[mi][ni], 0, 0, 0);
            }
        }
        __syncthreads();
    }

    if (swapped) {
        // D[n][m]: lane holds x-row s (fixed), 4 consecutive W-cols (d)
        bf16* out = qkv + (size_t)z * M_TOT * D_MODEL;
#pragma unroll
        for (int mi = 0; mi < 4; mi++) {
            int srow = m0 + wm * 64 + mi * 16 + ln;
            int b = srow >> 11, s = srow & 2047;
#pragma unroll
            for (int ni = 0; ni < 4; ni++) {
                int colz = (n0 & 1023) + wn * 64 + ni * 16 + qd * 4;
                f32x4 bb = *(const f32x4*)(bias + colz);
                int h = colz >> 6, d = colz & 63;
                bf16x4 p;
#pragma unroll
                for (int r = 0; r < 4; r++)
                    p[r] = (bf16)((acc[mi][ni][r] + bb[r]) * scale);
                *(bf16x4*)(out + (((size_t)(b * NHEAD + h)) * SEQ + s) * DKH + d) = p;
            }
        }
    } else {
        // D[m][n]: lane holds W-col d (fixed), 4 consecutive x-rows (s) -> V^T direct
#pragma unroll
        for (int ni = 0; ni < 4; ni++) {
            int colz = (n0 & 1023) + wn * 64 + ni * 16 + ln;
            float bcol = bias[colz];
            int h = colz >> 6, d = colz & 63;
#pragma unroll
            for (int mi = 0; mi < 4; mi++) {
                int rb = m0 + wm * 64 + mi * 16 + qd * 4;
                int b = rb >> 11, s = rb & 2047;
                bf16x4 p;
#pragma unroll
                for (int r = 0; r < 4; r++)
                    p[r] = (bf16)(acc[mi][ni][r] + bcol);
                *(bf16x4*)(vtg + (((size_t)(b * NHEAD + h)) * DKH + d) * SEQ + s) = p;
            }
        }
    }
}

// ---------------- flash attention v7: 32x32 MFMA, in-register P, VALU-trimmed ----------------
// R9 (v6) results: bank conflicts 8.39M->0, MFMA busy = 30us = arithmetic floor,
// but VALUBusy 58% (52us) -> issue-bound. R10 (v7): strip non-essential VALU:
//  * sc C-in = loop-invariant z16 (no per-tile accumulator zeroing)
//  * all 16 swizzled LDS read byte-offsets precomputed (lane-const)
//  * tile loop unrolled x2 -> buffer select is a ds offset immediate
//  * per-lane global staging bases precomputed; per-tile advance is SGPR-only
//  * no forced min-occupancy -> allocator may keep sc in VGPRs (no accvgpr shuttling)
//  * s_setprio(1) around MFMA clusters (T5: +4-7% attn, m191)
__global__ __launch_bounds__(256) void k_attn(const bf16* __restrict__ qg,
                                              const bf16* __restrict__ kg,
                                              const bf16* __restrict__ vtg,
                                              bf16* __restrict__ og) {
    __shared__ bf16 Ks[2 * 64 * 64];        // 16 KB (2 buffers)
    __shared__ bf16 Vs[2 * 64 * 64];        // 16 KB

    int tid = threadIdx.x;
    int lane = tid & 63, wid = tid >> 6;
    int ln32 = lane & 31, hi = lane >> 5;
    int bh = blockIdx.x;                    // x-fastest -> XCD pin per head
    int q0 = blockIdx.y * 128;
    int b = bh >> 4, h = bh & 15;

    const bf16* qp = qg + (size_t)bh * SEQ * DKH;
    const bf16* kp = kg + (size_t)bh * SEQ * DKH;
    const bf16* vp = vtg + (size_t)bh * DKH * SEQ;

    // ---- staging lane constants (two 16B chunks per lane per buffer) ----
    int cA = tid, cB = 256 + tid;
    int rowA = cA >> 3, rowB = cB >> 3;
    int chgA = (cA & 7) ^ ((rowA ^ (rowA >> 3)) & 7);
    int chgB = (cB & 7) ^ ((rowB ^ (rowB >> 3)) & 7);
    const bf16* kgA = kp + rowA * DKH + chgA * 8;
    const bf16* kgB = kp + rowB * DKH + chgB * 8;
    const bf16* vgA = vp + (size_t)rowA * SEQ + chgA * 8;
    const bf16* vgB = vp + (size_t)rowB * SEQ + chgB * 8;
    bf16* ldKA = Ks + (cA & ~63) * 8;
    bf16* ldKB = Ks + (cB & ~63) * 8;
    bf16* ldVA = Vs + (cA & ~63) * 8;
    bf16* ldVB = Vs + (cB & ~63) * 8;

    auto STAGE = [&](int bb, int kt) {
        async_ld16(kgA + (size_t)kt * DKH, ldKA + bb * 4096);
        async_ld16(vgA + kt,               ldVA + bb * 4096);
        async_ld16(kgB + (size_t)kt * DKH, ldKB + bb * 4096);
        async_ld16(vgB + kt,               ldVB + bb * 4096);
    };

    STAGE(0, 0);

    // ---- precomputed swizzled LDS read byte-offsets (all lane-const) ----
    unsigned koff[2][4], voff[2][4];
#pragma unroll
    for (int kb = 0; kb < 2; kb++) {
        int kr = kb * 32 + ln32;
        int sw = (kr ^ (kr >> 3)) & 7;
#pragma unroll
        for (int kk = 0; kk < 4; kk++)
            koff[kb][kk] = (unsigned)((kr * 64 + (((2 * kk + hi) ^ sw) * 8)) * 2);
    }
#pragma unroll
    for (int db = 0; db < 2; db++) {
        int vr = db * 32 + ln32;
        int sw = (vr ^ (vr >> 3)) & 7;
#pragma unroll
        for (int j = 0; j < 4; j++)
            voff[db][j] = (unsigned)((vr * 64 + (((2 * j + hi) ^ sw) * 8)) * 2);
    }

    // Q^T B-fragments (pre-scaled by log2e/8 in QKV GEMM): lane -> col q, k = kk*16+hi*8
    bf16x8 qa[4];
#pragma unroll
    for (int kk = 0; kk < 4; kk++)
        qa[kk] = *(const bf16x8*)(qp + (size_t)(q0 + wid * 32 + ln32) * DKH + kk * 16 + hi * 8);

    f32x16 o_acc[2];                         // O^T[d][q], d-blocks of 32
#pragma unroll
    for (int db = 0; db < 2; db++)
#pragma unroll
        for (int r = 0; r < 16; r++) o_acc[db][r] = 0.f;
    f32x4 lsum4 = {0.f, 0.f, 0.f, 0.f};

    f32x16 z16;                              // loop-invariant zero C-in for score MFMAs
#pragma unroll
    for (int r = 0; r < 16; r++) z16[r] = 0.f;

    asm volatile("s_waitcnt vmcnt(0)" ::: "memory");
    __builtin_amdgcn_s_barrier();

    auto TILE = [&](int bb) {
        const char* Kb = (const char*)Ks + bb * 8192;
        const char* Vb = (const char*)Vs + bb * 8192;

        // S^T = K·Q^T (log2 domain): two independent 32-key chains
        f32x16 sc[2];
        __builtin_amdgcn_s_setprio(1);
#pragma unroll
        for (int kb = 0; kb < 2; kb++) {
            bf16x8 kf0 = *(const bf16x8*)(Kb + koff[kb][0]);
            sc[kb] = __builtin_amdgcn_mfma_f32_32x32x16_bf16(kf0, qa[0], z16, 0, 0, 0);
#pragma unroll
            for (int kk = 1; kk < 4; kk++) {
                bf16x8 kf = *(const bf16x8*)(Kb + koff[kb][kk]);
                sc[kb] = __builtin_amdgcn_mfma_f32_32x32x16_bf16(kf, qa[kk], sc[kb], 0, 0, 0);
            }
        }
        __builtin_amdgcn_s_setprio(0);

        // per 32-key block: exp2 -> lsum -> pack -> permlane swaps -> PV
#pragma unroll
        for (int kb = 0; kb < 2; kb++) {
            unsigned pd[8];   // pd[j] = bf16 pair of keys crow(2j),crow(2j+1)
#pragma unroll
            for (int j = 0; j < 8; j++) {
                float e0 = __builtin_amdgcn_exp2f(sc[kb][2 * j]);
                float e1 = __builtin_amdgcn_exp2f(sc[kb][2 * j + 1]);
                lsum4[2 * (j & 1)]     += e0;
                lsum4[2 * (j & 1) + 1] += e1;
                pd[j] = pack2_bf16(e0, e1);
            }
#pragma unroll
            for (int ks = 0; ks < 2; ks++) {
                // swap(dst,src): dst.upper <-> src.lower; partners share q.
                unsigned a0 = pd[ks * 4 + 0], b0 = pd[ks * 4 + 2];
                unsigned a1 = pd[ks * 4 + 1], b1 = pd[ks * 4 + 3];
                asm volatile("v_permlane32_swap_b32 %0, %1" : "+v"(a0), "+v"(b0));
                asm volatile("v_permlane32_swap_b32 %0, %1" : "+v"(a1), "+v"(b1));
                union { unsigned u[4]; bf16x8 v; } pf;
                pf.u[0] = a0; pf.u[1] = a1; pf.u[2] = b0; pf.u[3] = b1;
                __builtin_amdgcn_s_setprio(1);
#pragma unroll
                for (int db = 0; db < 2; db++) {
                    bf16x8 vf = *(const bf16x8*)(Vb + voff[db][2 * kb + ks]);
                    o_acc[db] = __builtin_amdgcn_mfma_f32_32x32x16_bf16(vf, pf.v, o_acc[db], 0, 0, 0);
                }
                __builtin_amdgcn_s_setprio(0);
            }
        }
    };

    for (int t = 0; t < 32; t += 2) {
        STAGE(1, (t + 1) * 64);              // t+1 <= 31 always
        TILE(0);
        asm volatile("s_waitcnt vmcnt(0)" ::: "memory");
        __builtin_amdgcn_s_barrier();
        if (t < 30) STAGE(0, (t + 2) * 64);
        TILE(1);
        if (t < 30) {
            asm volatile("s_waitcnt vmcnt(0)" ::: "memory");
            __builtin_amdgcn_s_barrier();
        }
    }

    // l = sum over all 64 keys/iter: this lane's 32 + partner's 32
    float lsum = (lsum4[0] + lsum4[1]) + (lsum4[2] + lsum4[3]);
    float lt = lsum + __shfl_xor(lsum, 32, 64);
    float inv = 1.0f / lt;

    // O^T: reg r of o_acc[db] = O[d = (r&3)+8*(r>>2)+4*hi+32*db][q = ln32]
    int s = q0 + wid * 32 + ln32;
    size_t rowoff = ((size_t)b * SEQ + s) * D_MODEL + h * DKH;
#pragma unroll
    for (int db = 0; db < 2; db++)
#pragma unroll
        for (int q4 = 0; q4 < 4; q4++) {
            bf16x4 pv4;
#pragma unroll
            for (int j = 0; j < 4; j++) pv4[j] = (bf16)(o_acc[db][q4 * 4 + j] * inv);
            *(bf16x4*)(og + rowoff + db * 32 + q4 * 8 + hi * 4) = pv4;
        }
}

// ---------------- output GEMM: O[8192x1024] @ Wo + bo -> fp32 ----------------
// BK=64 + XCD-swizzled grid (x=m, y=n). Transposed epilogue, float4 stores.
__global__ __launch_bounds__(256) void k_gemm_out(const bf16* __restrict__ ob,
                                                  const bf16* __restrict__ wot,
                                                  const float* __restrict__ bo,
                                                  float* __restrict__ out) {
    __shared__ bf16 As[2 * 128 * 32];
    __shared__ bf16 Bs[2 * 128 * 32];

    int tid = threadIdx.x;
    int lane = tid & 63, wid = tid >> 6;
    int ln = lane & 15, qd = lane >> 4;
    int wm = wid >> 1, wn = wid & 1;
    int m0 = blockIdx.x * 128, n0 = blockIdx.y * 128;

    f32x4 zero4 = {0.f, 0.f, 0.f, 0.f};
    f32x4 acc[4][4];
#pragma unroll
    for (int i = 0; i < 4; i++)
#pragma unroll
        for (int j = 0; j < 4; j++) acc[i][j] = zero4;

    for (int k0 = 0; k0 < D_MODEL; k0 += 64) {
#pragma unroll
        for (int t = 0; t < 4; t++) {
            int c = t * 256 + tid;
            int ch = c >> 9, w = c & 511;
            int row = w >> 2, part = w & 3;
            async_ld16(ob + (size_t)(m0 + row) * D_MODEL + k0 + ch * 32 + part * 8,
                       As + ch * 4096 + (w & ~63) * 8);
            async_ld16(wot + (size_t)(n0 + row) * D_MODEL + k0 + ch * 32 + part * 8,
                       Bs + ch * 4096 + (w & ~63) * 8);
        }
        __syncthreads();
#pragma unroll
        for (int kc = 0; kc < 2; kc++) {
            bf16x8 af[4], bfr[4];
#pragma unroll
            for (int mi = 0; mi < 4; mi++)
                af[mi] = *(const bf16x8*)(As + kc * 4096 + (wm * 64 + mi * 16 + ln) * 32 + qd * 8);
#pragma unroll
            for (int ni = 0; ni < 4; ni++)
                bfr[ni] = *(const bf16x8*)(Bs + kc * 4096 + (wn * 64 + ni * 16 + ln) * 32 + qd * 8);
#pragma unroll
            for (int mi = 0; mi < 4; mi++)
#pragma unroll
                for (int ni = 0; ni < 4; ni++)
                    acc[mi][ni] = __builtin_amdgcn_mfma_f32_16x16x32_bf16(bfr[ni], af[mi],
                                                                          acc[mi][ni], 0, 0, 0);
        }
        __syncthreads();
    }

#pragma unroll
    for (int mi = 0; mi < 4; mi++) {
        int row = m0 + wm * 64 + mi * 16 + ln;
#pragma unroll
        for (int ni = 0; ni < 4; ni++) {
            int col4 = n0 + wn * 64 + ni * 16 + qd * 4;
            f32x4 bb = *(const f32x4*)(bo + col4);
            f32x4 v;
#pragma unroll
            for (int r = 0; r < 4; r++) v[r] = acc[mi][ni][r] + bb[r];
            *(f32x4*)(out + (size_t)row * D_MODEL + col4) = v;
        }
    }
}

extern "C" void kernel_launch(void* const* d_in, const int* in_sizes, int n_in,
                              void* d_out, int out_size, void* d_ws, size_t ws_size,
                              hipStream_t stream) {
    const float* x  = (const float*)d_in[0];
    const float* wq = (const float*)d_in[1];
    const float* bq = (const float*)d_in[2];
    const float* wk = (const float*)d_in[3];
    const float* bk = (const float*)d_in[4];
    const float* wv = (const float*)d_in[5];
    const float* bv = (const float*)d_in[6];
    const float* wo = (const float*)d_in[7];
    const float* bo = (const float*)d_in[8];
    float* out = (float*)d_out;

    char* ws = (char*)d_ws;
    bf16* xb  = (bf16*)ws;                    // 16.8 MB (reused as og after QKV GEMM)
    bf16* wt  = (bf16*)(ws + 16777216);       //  8.4 MB (wq,wk,wv,wo transposed, contiguous)
    bf16* qkv = (bf16*)(ws + 25165824);       // Q,K
    bf16* vtg = (bf16*)(ws + 75497472);       // V^T written directly by GEMM
    bf16* og  = xb;

    k_cvt<<<dim3(8192 + 4096), dim3(256), 0, stream>>>(x, xb, wq, wk, wv, wo, wt);
    k_gemm_qkv<<<dim3(64, 24), dim3(256), 0, stream>>>(xb, wt, bq, bk, bv, qkv, vtg);
    k_attn<<<dim3(64, 16), dim3(256), 0, stream>>>(qkv, qkv + (size_t)M_TOT * D_MODEL, vtg, og);
    k_gemm_out<<<dim3(64, 8), dim3(256), 0, stream>>>(og, wt + 3 * (size_t)D_MODEL * D_MODEL,
                                                      bo, out);
}

// Round 4
// 281.590 us; speedup vs baseline: 1.0451x; 1.0451x over previous
//
#include <hip/hip_runtime.h>
#include <hip/hip_bf16.h>
#include <cstdint>

#define D_MODEL 1024
#define NHEAD 16
#define DKH 64
#define BATCH 4
#define SEQ 2048
#define M_TOT (BATCH*SEQ)   // 8192

typedef __bf16 bf16;
typedef __bf16 bf16x8 __attribute__((ext_vector_type(8)));
typedef __bf16 bf16x4 __attribute__((ext_vector_type(4)));
typedef float  f32x4  __attribute__((ext_vector_type(4)));

// async global->LDS, 16B per lane. LDS dest must be wave-uniform base; HW adds lane*16.
__device__ __forceinline__ void async_ld16(const void* g, void* l) {
    __builtin_amdgcn_global_load_lds(
        (__attribute__((address_space(1))) void*)(uintptr_t)g,
        (__attribute__((address_space(3))) void*)(uintptr_t)l,
        16, 0, 0);
}

// ---------------- merged convert: x fp32->bf16 (blocks 0..8191) and
// weight convert+transpose W[K][N] fp32 -> Wt[N][K] bf16 (blocks 8192..12287) ----------------
__global__ __launch_bounds__(256) void k_cvt(const float* __restrict__ x,
                                             bf16* __restrict__ xb,
                                             const float* __restrict__ wq,
                                             const float* __restrict__ wk,
                                             const float* __restrict__ wv,
                                             const float* __restrict__ wo,
                                             bf16* __restrict__ wt) {
    __shared__ float t[32][33];
    int bid = blockIdx.x;
    if (bid < 8192) {
        int i = (bid * 256 + threadIdx.x) * 4;
        float4 f = *(const float4*)(x + i);
        bf16x4 o;
        o[0] = (bf16)f.x; o[1] = (bf16)f.y; o[2] = (bf16)f.z; o[3] = (bf16)f.w;
        *(bf16x4*)(xb + i) = o;
    } else {
        int wb = bid - 8192;                  // 0..4095
        int z = wb >> 10;
        int rem = wb & 1023;
        const float* W = (z == 0) ? wq : (z == 1) ? wk : (z == 2) ? wv : wo;
        bf16* T = wt + (size_t)z * D_MODEL * D_MODEL;
        int tx = threadIdx.x & 31, ty = threadIdx.x >> 5;   // (32,8)
        int bx = (rem & 31) * 32, by = (rem >> 5) * 32;
#pragma unroll
        for (int i = 0; i < 4; i++)
            t[ty + i * 8][tx] = W[(size_t)(by + ty + i * 8) * D_MODEL + bx + tx];
        __syncthreads();
#pragma unroll
        for (int i = 0; i < 4; i++)
            T[(size_t)(bx + ty + i * 8) * D_MODEL + by + tx] = (bf16)t[tx][ty + i * 8];
    }
}

// ======================= ring-6 counted-vmcnt GEMM core =======================
// R12 (= R11 hardened): 6-slot ring of BK=32 units (A-panel 8KB + B-panel 8KB
// per K-step), stage distance 2 steps, ONE barrier + vmcnt(4) per step (never 0
// in-loop). Safety: slot written at step t was last read at step t-1; stage is
// issued AFTER barrier(t) which happens-after all reads(t-1). vmcnt is FIFO: at
// the step-t wait, in-flight = 4 loads from step t-1 + 4 from t-2; vmcnt(4) =>
// the 4 oldest (this step's data) have landed — in EVERY wave, because the wait
// precedes the barrier (m201 pattern). Hardening vs R11: (a) compiler memory
// fence after each s_barrier so ds_reads can't hoist above it; (b) ring indices
// advance by increment-wrap (no runtime modulo).
// Swizzle: 4 chunks of 16B per 64B row; ch ^= (row^(row>>2))&3 applied on the
// GLOBAL source (gload_lds writes linearly) and on the ds_read chunk (rule 21).
// Read pattern (16 row-lanes x 4 chunk-groups) -> 2-way bank alias = free (m136).

// ---------------- fused QKV GEMM, z-merged + XCD-swizzled ----------------
__global__ __launch_bounds__(256) void k_gemm_qkv(const bf16* __restrict__ xb,
                                                  const bf16* __restrict__ wt,
                                                  const float* __restrict__ bq,
                                                  const float* __restrict__ bk,
                                                  const float* __restrict__ bv,
                                                  bf16* __restrict__ qkv,
                                                  bf16* __restrict__ vtg) {
    __shared__ bf16 S[6 * 4096];   // 48 KB: 6 ring slots of 8 KB ([128][32] bf16)

    int tid = threadIdx.x;
    int lane = tid & 63, wid = tid >> 6;
    int ln = lane & 15, qd = lane >> 4;
    int wm = wid >> 1, wn = wid & 1;
    int m0 = blockIdx.x * 128;                 // m-tile (x-fastest -> XCD pin)
    int n0 = blockIdx.y * 128;                 // global col in [0,3072)
    int z = n0 >> 10;
    const float* bias = (z == 0) ? bq : (z == 1) ? bk : bv;
    float scale = (z == 0) ? 0.125f * 1.44269504088896f : 1.0f;  // 1/sqrt(Dk)*log2e folded into Q
    bool swapped = (z < 2);

    const bf16* Ag = xb + (size_t)m0 * D_MODEL;
    const bf16* Bg = wt + (size_t)n0 * D_MODEL;

    // stage one 8KB unit ([128 rows][32 k] window at k0) into ring slot
    auto STAGEU = [&](const bf16* gbase, int k0, int slot) {
#pragma unroll
        for (int i = 0; i < 2; i++) {
            int c = i * 256 + tid;                        // 0..511 chunks of 16B
            int row = c >> 2, chl = c & 3;
            int chg = chl ^ ((row ^ (row >> 2)) & 3);     // inverse swizzle on source
            async_ld16(gbase + (size_t)row * D_MODEL + k0 + chg * 8,
                       S + slot * 4096 + (c & ~63) * 8);
        }
    };

    f32x4 zero4 = {0.f, 0.f, 0.f, 0.f};
    f32x4 acc[4][4];
#pragma unroll
    for (int i = 0; i < 4; i++)
#pragma unroll
        for (int j = 0; j < 4; j++) acc[i][j] = zero4;

    // lane-const swizzled read offsets (within an 8KB slot, in elements)
    unsigned aoff[4], boff[4];
#pragma unroll
    for (int mi = 0; mi < 4; mi++) {
        int row = wm * 64 + mi * 16 + ln;
        aoff[mi] = (unsigned)(row * 32 + ((qd ^ ((row ^ (row >> 2)) & 3)) * 8));
    }
#pragma unroll
    for (int ni = 0; ni < 4; ni++) {
        int row = wn * 64 + ni * 16 + ln;
        boff[ni] = (unsigned)(row * 32 + ((qd ^ ((row ^ (row >> 2)) & 3)) * 8));
    }

    // prologue: units 0..3 (K-steps 0,1), oldest-first
    STAGEU(Ag, 0, 0);  STAGEU(Bg, 0, 1);
    STAGEU(Ag, 32, 2); STAGEU(Bg, 32, 3);

    const int NSTEP = D_MODEL / 32;            // 32
    int ca = 0;                                // compute slot-pair (slots 2*ca, 2*ca+1)
    int cp = 2;                                // stage slot-pair for step t+2
    for (int t = 0; t < NSTEP - 1; t++) {
        asm volatile("s_waitcnt vmcnt(4)" ::: "memory");
        __builtin_amdgcn_s_barrier();
        asm volatile("" ::: "memory");         // pin reads after barrier
        if (t < NSTEP - 2) {                   // stage units for step t+2
            STAGEU(Ag, (t + 2) * 32, 2 * cp);
            STAGEU(Bg, (t + 2) * 32, 2 * cp + 1);
        }
        bf16x8 af[4], bfr[4];
#pragma unroll
        for (int mi = 0; mi < 4; mi++)
            af[mi] = *(const bf16x8*)(S + (2 * ca) * 4096 + aoff[mi]);
#pragma unroll
        for (int ni = 0; ni < 4; ni++)
            bfr[ni] = *(const bf16x8*)(S + (2 * ca + 1) * 4096 + boff[ni]);
        if (swapped) {
#pragma unroll
            for (int mi = 0; mi < 4; mi++)
#pragma unroll
                for (int ni = 0; ni < 4; ni++)
                    acc[mi][ni] = __builtin_amdgcn_mfma_f32_16x16x32_bf16(bfr[ni], af[mi],
                                                                          acc[mi][ni], 0, 0, 0);
        } else {
#pragma unroll
            for (int mi = 0; mi < 4; mi++)
#pragma unroll
                for (int ni = 0; ni < 4; ni++)
                    acc[mi][ni] = __builtin_amdgcn_mfma_f32_16x16x32_bf16(af[mi], bfr[ni],
                                                                          acc[mi][ni], 0, 0, 0);
        }
        ca = (ca == 2) ? 0 : ca + 1;
        cp = (cp == 2) ? 0 : cp + 1;
    }
    {   // peeled final step: nothing newer in flight -> full drain required
        asm volatile("s_waitcnt vmcnt(0)" ::: "memory");
        __builtin_amdgcn_s_barrier();
        asm volatile("" ::: "memory");
        bf16x8 af[4], bfr[4];
#pragma unroll
        for (int mi = 0; mi < 4; mi++)
            af[mi] = *(const bf16x8*)(S + (2 * ca) * 4096 + aoff[mi]);
#pragma unroll
        for (int ni = 0; ni < 4; ni++)
            bfr[ni] = *(const bf16x8*)(S + (2 * ca + 1) * 4096 + boff[ni]);
        if (swapped) {
#pragma unroll
            for (int mi = 0; mi < 4; mi++)
#pragma unroll
                for (int ni = 0; ni < 4; ni++)
                    acc[mi][ni] = __builtin_amdgcn_mfma_f32_16x16x32_bf16(bfr[ni], af[mi],
                                                                          acc[mi][ni], 0, 0, 0);
        } else {
#pragma unroll
            for (int mi = 0; mi < 4; mi++)
#pragma unroll
                for (int ni = 0; ni < 4; ni++)
                    acc[mi][ni] = __builtin_amdgcn_mfma_f32_16x16x32_bf16(af[mi], bfr[ni],
                                                                          acc[mi][ni], 0, 0, 0);
        }
    }

    if (swapped) {
        // D[n][m]: lane holds x-row s (fixed), 4 consecutive W-cols (d)
        bf16* out = qkv + (size_t)z * M_TOT * D_MODEL;
#pragma unroll
        for (int mi = 0; mi < 4; mi++) {
            int srow = m0 + wm * 64 + mi * 16 + ln;
            int b = srow >> 11, s = srow & 2047;
#pragma unroll
            for (int ni = 0; ni < 4; ni++) {
                int colz = (n0 & 1023) + wn * 64 + ni * 16 + qd * 4;
                f32x4 bb = *(const f32x4*)(bias + colz);
                int h = colz >> 6, d = colz & 63;
                bf16x4 p;
#pragma unroll
                for (int r = 0; r < 4; r++)
                    p[r] = (bf16)((acc[mi][ni][r] + bb[r]) * scale);
                *(bf16x4*)(out + (((size_t)(b * NHEAD + h)) * SEQ + s) * DKH + d) = p;
            }
        }
    } else {
        // D[m][n]: lane holds W-col d (fixed), 4 consecutive x-rows (s) -> V^T direct
#pragma unroll
        for (int ni = 0; ni < 4; ni++) {
            int colz = (n0 & 1023) + wn * 64 + ni * 16 + ln;
            float bcol = bias[colz];
            int h = colz >> 6, d = colz & 63;
#pragma unroll
            for (int mi = 0; mi < 4; mi++) {
                int rb = m0 + wm * 64 + mi * 16 + qd * 4;
                int b = rb >> 11, s = rb & 2047;
                bf16x4 p;
#pragma unroll
                for (int r = 0; r < 4; r++)
                    p[r] = (bf16)(acc[mi][ni][r] + bcol);
                *(bf16x4*)(vtg + (((size_t)(b * NHEAD + h)) * DKH + d) * SEQ + s) = p;
            }
        }
    }
}

// ---------------- flash attention v5 (best measured, 87 us) ----------------
// R8: (1) grid swapped to (64 bh, 16 q-tiles): id%8 = bh%8 -> all 16 q-blocks
// of one head share an XCD; K/V HBM-fetched once, re-reads are L2 hits ->
// shorter pre-barrier vmcnt drain. (2) PROW 40->36 (18 words: ln*18 mod 32
// hits all 16 residues -> no ln/ln+8 bank alias on Ps). pf reads = 2x b64.
// R9/R10 lesson: 32x32+in-reg-P variants hit the 30us MFMA floor but paid
// +21us VALU (AGPR shuttling, pack, lsum) and/or occupancy (>64 VGPR cliff).
#define PROW 36
__global__ __launch_bounds__(256, 4) void k_attn(const bf16* __restrict__ qg,
                                                 const bf16* __restrict__ kg,
                                                 const bf16* __restrict__ vtg,
                                                 bf16* __restrict__ og) {
    __shared__ bf16 Ks[2 * 64 * 32];        // 8 KB
    __shared__ bf16 Vs[2 * 64 * 32];        // 8 KB
    __shared__ bf16 Ps[4 * 2 * 32 * PROW];  // 18 KB

    int tid = threadIdx.x;
    int lane = tid & 63, wid = tid >> 6;
    int ln = lane & 15, qd = lane >> 4;
    int bh = blockIdx.x;                    // x-fastest -> XCD pin per head
    int q0 = blockIdx.y * 128;
    int b = bh >> 4, h = bh & 15;

    const bf16* qp = qg + (size_t)bh * SEQ * DKH;
    const bf16* kp = kg + (size_t)bh * SEQ * DKH;
    const bf16* vp = vtg + (size_t)bh * DKH * SEQ;

    // Q fragments (pre-scaled by log2e/8), used as B operand of swapped score MFMA
    bf16x8 qa[2][2];
#pragma unroll
    for (int mi = 0; mi < 2; mi++)
#pragma unroll
        for (int kc = 0; kc < 2; kc++)
            qa[mi][kc] = *(const bf16x8*)(qp + (size_t)(q0 + wid * 32 + mi * 16 + ln) * DKH
                                          + kc * 32 + qd * 8);

    // ones B-fragment: B[k][0]=1 for all k -> lanes with ln==0 hold 1.0
    bf16 onev = (bf16)((ln == 0) ? 1.0f : 0.0f);
    bf16x8 ones_frag = {onev, onev, onev, onev, onev, onev, onev, onev};

    f32x4 zero4 = {0.f, 0.f, 0.f, 0.f};
    f32x4 o_acc[2][4];
    f32x4 l_acc[2];
#pragma unroll
    for (int mi = 0; mi < 2; mi++) {
        l_acc[mi] = zero4;
#pragma unroll
        for (int nd = 0; nd < 4; nd++) o_acc[mi][nd] = zero4;
    }

    bf16* Pw = Ps + wid * 2 * 32 * PROW;

    for (int kt = 0; kt < SEQ; kt += 64) {
        // stage K tile -> Ks[2][64][32] and Vt tile -> Vs[2][64][32] (chunked, 64B rows)
#pragma unroll
        for (int t = 0; t < 2; t++) {
            int c = t * 256 + tid;                 // 0..511, 16B each
            int ch = c >> 8, w = c & 255;
            int row = w >> 2, part = w & 3;
            async_ld16(kp + (size_t)(kt + row) * DKH + ch * 32 + part * 8,
                       Ks + (c & ~63) * 8);
            async_ld16(vp + (size_t)row * SEQ + kt + ch * 32 + part * 8,
                       Vs + (c & ~63) * 8);
        }
        __syncthreads();

        // S^T = K Q^T (log2 domain): A=K-frag, B=Q-frag; row=key qd*4+r, col=q=ln
        f32x4 sc[2][4];
#pragma unroll
        for (int mi = 0; mi < 2; mi++)
#pragma unroll
            for (int ni = 0; ni < 4; ni++) sc[mi][ni] = zero4;
#pragma unroll
        for (int kc = 0; kc < 2; kc++) {
#pragma unroll
            for (int ni = 0; ni < 4; ni++) {
                bf16x8 kb = *(const bf16x8*)(Ks + kc * 2048 + (ni * 16 + ln) * 32 + qd * 8);
#pragma unroll
                for (int mi = 0; mi < 2; mi++)
                    sc[mi][ni] = __builtin_amdgcn_mfma_f32_16x16x32_bf16(kb, qa[mi][kc],
                                                                         sc[mi][ni], 0, 0, 0);
            }
        }

        // P = exp2(S): lane owns 4 consecutive keys of P-row q=mi*16+ln -> b64 write
#pragma unroll
        for (int mi = 0; mi < 2; mi++) {
#pragma unroll
            for (int ni = 0; ni < 4; ni++) {
                bf16x4 p4;
#pragma unroll
                for (int r = 0; r < 4; r++)
                    p4[r] = (bf16)__builtin_amdgcn_exp2f(sc[mi][ni][r]);
                *(bf16x4*)(Pw + (ni >> 1) * 32 * PROW + (mi * 16 + ln) * PROW
                           + (ni & 1) * 16 + qd * 4) = p4;
            }
        }

        // O += P V ; l += P * ones  (A=P from LDS round-trip; 2x b64 reads, 72B rows)
#pragma unroll
        for (int kc2 = 0; kc2 < 2; kc2++) {
            bf16x8 pf[2];
#pragma unroll
            for (int mi = 0; mi < 2; mi++) {
                const bf16* pr = Pw + kc2 * 32 * PROW + (mi * 16 + ln) * PROW + qd * 8;
                bf16x4 lo = *(const bf16x4*)(pr);
                bf16x4 hi = *(const bf16x4*)(pr + 4);
                pf[mi][0] = lo[0]; pf[mi][1] = lo[1]; pf[mi][2] = lo[2]; pf[mi][3] = lo[3];
                pf[mi][4] = hi[0]; pf[mi][5] = hi[1]; pf[mi][6] = hi[2]; pf[mi][7] = hi[3];
                l_acc[mi] = __builtin_amdgcn_mfma_f32_16x16x32_bf16(pf[mi], ones_frag,
                                                                    l_acc[mi], 0, 0, 0);
            }
#pragma unroll
            for (int nd = 0; nd < 4; nd++) {
                bf16x8 vf = *(const bf16x8*)(Vs + kc2 * 2048 + (nd * 16 + ln) * 32 + qd * 8);
#pragma unroll
                for (int mi = 0; mi < 2; mi++)
                    o_acc[mi][nd] = __builtin_amdgcn_mfma_f32_16x16x32_bf16(pf[mi], vf,
                                                                            o_acc[mi][nd], 0, 0, 0);
            }
        }
        __syncthreads();
    }

    // normalize and store O as bf16 [B,S,H*Dk]; row-sum lives in col 0 (lanes ln==0)
#pragma unroll
    for (int mi = 0; mi < 2; mi++) {
#pragma unroll
        for (int r = 0; r < 4; r++) {
            float lsum = __shfl(l_acc[mi][r], lane & 48, 64);  // broadcast from ln==0 of this qd
            float inv = 1.0f / lsum;
            int s = q0 + wid * 32 + mi * 16 + qd * 4 + r;
            size_t rowoff = ((size_t)b * SEQ + s) * D_MODEL + h * DKH;
#pragma unroll
            for (int nd = 0; nd < 4; nd++)
                og[rowoff + nd * 16 + ln] = (bf16)(o_acc[mi][nd][r] * inv);
        }
    }
}

// ---------------- output GEMM: O[8192x1024] @ Wo + bo -> fp32 (ring-6) ----------------
__global__ __launch_bounds__(256) void k_gemm_out(const bf16* __restrict__ ob,
                                                  const bf16* __restrict__ wot,
                                                  const float* __restrict__ bo,
                                                  float* __restrict__ out) {
    __shared__ bf16 S[6 * 4096];   // 48 KB ring

    int tid = threadIdx.x;
    int lane = tid & 63, wid = tid >> 6;
    int ln = lane & 15, qd = lane >> 4;
    int wm = wid >> 1, wn = wid & 1;
    int m0 = blockIdx.x * 128, n0 = blockIdx.y * 128;

    const bf16* Ag = ob + (size_t)m0 * D_MODEL;
    const bf16* Bg = wot + (size_t)n0 * D_MODEL;

    auto STAGEU = [&](const bf16* gbase, int k0, int slot) {
#pragma unroll
        for (int i = 0; i < 2; i++) {
            int c = i * 256 + tid;
            int row = c >> 2, chl = c & 3;
            int chg = chl ^ ((row ^ (row >> 2)) & 3);
            async_ld16(gbase + (size_t)row * D_MODEL + k0 + chg * 8,
                       S + slot * 4096 + (c & ~63) * 8);
        }
    };

    f32x4 zero4 = {0.f, 0.f, 0.f, 0.f};
    f32x4 acc[4][4];
#pragma unroll
    for (int i = 0; i < 4; i++)
#pragma unroll
        for (int j = 0; j < 4; j++) acc[i][j] = zero4;

    unsigned aoff[4], boff[4];
#pragma unroll
    for (int mi = 0; mi < 4; mi++) {
        int row = wm * 64 + mi * 16 + ln;
        aoff[mi] = (unsigned)(row * 32 + ((qd ^ ((row ^ (row >> 2)) & 3)) * 8));
    }
#pragma unroll
    for (int ni = 0; ni < 4; ni++) {
        int row = wn * 64 + ni * 16 + ln;
        boff[ni] = (unsigned)(row * 32 + ((qd ^ ((row ^ (row >> 2)) & 3)) * 8));
    }

    STAGEU(Ag, 0, 0);  STAGEU(Bg, 0, 1);
    STAGEU(Ag, 32, 2); STAGEU(Bg, 32, 3);

    const int NSTEP = D_MODEL / 32;
    int ca = 0, cp = 2;
    for (int t = 0; t < NSTEP - 1; t++) {
        asm volatile("s_waitcnt vmcnt(4)" ::: "memory");
        __builtin_amdgcn_s_barrier();
        asm volatile("" ::: "memory");
        if (t < NSTEP - 2) {
            STAGEU(Ag, (t + 2) * 32, 2 * cp);
            STAGEU(Bg, (t + 2) * 32, 2 * cp + 1);
        }
        bf16x8 af[4], bfr[4];
#pragma unroll
        for (int mi = 0; mi < 4; mi++)
            af[mi] = *(const bf16x8*)(S + (2 * ca) * 4096 + aoff[mi]);
#pragma unroll
        for (int ni = 0; ni < 4; ni++)
            bfr[ni] = *(const bf16x8*)(S + (2 * ca + 1) * 4096 + boff[ni]);
#pragma unroll
        for (int mi = 0; mi < 4; mi++)
#pragma unroll
            for (int ni = 0; ni < 4; ni++)
                acc[mi][ni] = __builtin_amdgcn_mfma_f32_16x16x32_bf16(bfr[ni], af[mi],
                                                                      acc[mi][ni], 0, 0, 0);
        ca = (ca == 2) ? 0 : ca + 1;
        cp = (cp == 2) ? 0 : cp + 1;
    }
    {
        asm volatile("s_waitcnt vmcnt(0)" ::: "memory");
        __builtin_amdgcn_s_barrier();
        asm volatile("" ::: "memory");
        bf16x8 af[4], bfr[4];
#pragma unroll
        for (int mi = 0; mi < 4; mi++)
            af[mi] = *(const bf16x8*)(S + (2 * ca) * 4096 + aoff[mi]);
#pragma unroll
        for (int ni = 0; ni < 4; ni++)
            bfr[ni] = *(const bf16x8*)(S + (2 * ca + 1) * 4096 + boff[ni]);
#pragma unroll
        for (int mi = 0; mi < 4; mi++)
#pragma unroll
            for (int ni = 0; ni < 4; ni++)
                acc[mi][ni] = __builtin_amdgcn_mfma_f32_16x16x32_bf16(bfr[ni], af[mi],
                                                                      acc[mi][ni], 0, 0, 0);
    }

#pragma unroll
    for (int mi = 0; mi < 4; mi++) {
        int row = m0 + wm * 64 + mi * 16 + ln;
#pragma unroll
        for (int ni = 0; ni < 4; ni++) {
            int col4 = n0 + wn * 64 + ni * 16 + qd * 4;
            f32x4 bb = *(const f32x4*)(bo + col4);
            f32x4 v;
#pragma unroll
            for (int r = 0; r < 4; r++) v[r] = acc[mi][ni][r] + bb[r];
            *(f32x4*)(out + (size_t)row * D_MODEL + col4) = v;
        }
    }
}

extern "C" void kernel_launch(void* const* d_in, const int* in_sizes, int n_in,
                              void* d_out, int out_size, void* d_ws, size_t ws_size,
                              hipStream_t stream) {
    const float* x  = (const float*)d_in[0];
    const float* wq = (const float*)d_in[1];
    const float* bq = (const float*)d_in[2];
    const float* wk = (const float*)d_in[3];
    const float* bk = (const float*)d_in[4];
    const float* wv = (const float*)d_in[5];
    const float* bv = (const float*)d_in[6];
    const float* wo = (const float*)d_in[7];
    const float* bo = (const float*)d_in[8];
    float* out = (float*)d_out;

    char* ws = (char*)d_ws;
    bf16* xb  = (bf16*)ws;                    // 16.8 MB (reused as og after QKV GEMM)
    bf16* wt  = (bf16*)(ws + 16777216);       //  8.4 MB (wq,wk,wv,wo transposed, contiguous)
    bf16* qkv = (bf16*)(ws + 25165824);       // Q,K
    bf16* vtg = (bf16*)(ws + 75497472);       // V^T written directly by GEMM
    bf16* og  = xb;

    k_cvt<<<dim3(8192 + 4096), dim3(256), 0, stream>>>(x, xb, wq, wk, wv, wo, wt);
    k_gemm_qkv<<<dim3(64, 24), dim3(256), 0, stream>>>(xb, wt, bq, bk, bv, qkv, vtg);
    k_attn<<<dim3(64, 16), dim3(256), 0, stream>>>(qkv, qkv + (size_t)M_TOT * D_MODEL, vtg, og);
    k_gemm_out<<<dim3(64, 8), dim3(256), 0, stream>>>(og, wt + 3 * (size_t)D_MODEL * D_MODEL,
                                                      bo, out);
}